// Round 1
// baseline (96.994 us; speedup 1.0000x reference)
//
#include <hip/hip_runtime.h>
#include <stdint.h>

#define NPTS 8192
#define BATCH 4

typedef __attribute__((ext_vector_type(8))) short bf16x8;   // 8 bf16 = 4 VGPRs
typedef __attribute__((ext_vector_type(16))) float f32x16;  // 32x32 MFMA acc

struct Accum {
  float count[4];    // [b] valid-point counts
  float minsum[8];   // [dir*4+b] masked min sums
  unsigned ticket;   // last-block-done counter (reset by prep each launch)
  unsigned pad[3];
};

__device__ __forceinline__ unsigned short f2bf(float x) {  // RNE fp32->bf16
  union { float f; unsigned u; } v; v.f = x;
  unsigned r = v.u + 0x7FFFu + ((v.u >> 16) & 1u);
  return (unsigned short)(r >> 16);
}
__device__ __forceinline__ float bf2f(unsigned short h) {
  union { float f; unsigned u; } v; v.u = ((unsigned)h) << 16;
  return v.f;
}

using as1_t = __attribute__((address_space(1))) const unsigned int;
using as3_t = __attribute__((address_space(3))) unsigned int;
__device__ __forceinline__ void lds_load16(const void* g, void* l) {
  __builtin_amdgcn_global_load_lds((as1_t*)g, (as3_t*)l, 16, 0, 0);
}

// Pack layout (fragment order): per 32-point tile T, 64 chunks of 16 B:
// chunk T*64 + h*32 + n = K-slots [8h..8h+7] of point T*32+n  (== chunk T*64+lane
// for MFMA lane = h*32+n, so frag load is lane-consecutive 16 B -> conflict-free).
// A (ref):   k0-3=[-2x_h,-2x_h,-2x_l,-2x_l] k4-7=y k8-11=z k12-14=3-split(norm+pen) k15=0
// B (query): k0-3=[x_h,x_l,x_h,x_l]         k4-7=y k8-11=z k12-14=[1,1,1]          k15=0
// => D[ref m][query n] = (norm_r + pen) - 2 q.r  (query norm added in epilogue;
// exact hi/lo bf16 product pairing, norm exact to ~4e-7)
__device__ __forceinline__ void writeA(uint4* P, int T, int n,
                                       float x, float y, float z, float nn) {
  float ax = -2.f * x, ay = -2.f * y, az = -2.f * z;
  unsigned xh = f2bf(ax), xl = f2bf(ax - bf2f(xh));
  unsigned yh = f2bf(ay), yl = f2bf(ay - bf2f(yh));
  unsigned zh = f2bf(az), zl = f2bf(az - bf2f(zh));
  unsigned nh = f2bf(nn);
  float rem = nn - bf2f((unsigned short)nh);
  unsigned nm = f2bf(rem);
  unsigned nl = f2bf(rem - bf2f((unsigned short)nm));
  uint4 h0, h1;
  h0.x = xh | (xh << 16); h0.y = xl | (xl << 16);
  h0.z = yh | (yh << 16); h0.w = yl | (yl << 16);
  h1.x = zh | (zh << 16); h1.y = zl | (zl << 16);
  h1.z = nh | (nm << 16); h1.w = nl;
  P[T * 64 + n] = h0;
  P[T * 64 + 32 + n] = h1;
}
__device__ __forceinline__ void writeB(uint4* P, int T, int n,
                                       float x, float y, float z) {
  unsigned xh = f2bf(x), xl = f2bf(x - bf2f((unsigned short)xh));
  unsigned yh = f2bf(y), yl = f2bf(y - bf2f((unsigned short)yh));
  unsigned zh = f2bf(z), zl = f2bf(z - bf2f((unsigned short)zh));
  const unsigned ONE = 0x3F80u;
  unsigned ux = xh | (xl << 16), uy = yh | (yl << 16), uz = zh | (zl << 16);
  uint4 h0, h1;
  h0.x = ux; h0.y = ux; h0.z = uy; h0.w = uy;
  h1.x = uz; h1.y = uz; h1.z = ONE | (ONE << 16); h1.w = ONE;
  P[T * 64 + n] = h0;
  P[T * 64 + 32 + n] = h1;
}

// 512 blocks x 64 threads: 2 blocks/CU (vs old 0.5) for the latency-bound pack.
__global__ __launch_bounds__(64) void prep_kernel(
    const float* __restrict__ pred, const float* __restrict__ target,
    const int* __restrict__ mask, const float* __restrict__ points,
    uint4* __restrict__ Apred, uint4* __restrict__ Aclean,
    uint4* __restrict__ Bclean, uint4* __restrict__ Bpred,
    float* __restrict__ qnClean, float* __restrict__ qnPred,
    unsigned* __restrict__ minbuf, float* __restrict__ l1part,
    Accum* __restrict__ acc) {
  int tid = threadIdx.x;
  int g = blockIdx.x * 64 + tid;  // 512*64 = BATCH*NPTS
  if (g < 16) ((unsigned*)acc)[g] = 0u;  // zero counts/minsums/ticket
  // init per-query running-min buffer to +inf (8 slices x 8192 = 2*32768)
  minbuf[g] = 0x7F800000u;
  minbuf[g + BATCH * NPTS] = 0x7F800000u;

  float px = pred[3 * g], py = pred[3 * g + 1], pz = pred[3 * g + 2];
  float tx = target[3 * g], ty = target[3 * g + 1], tz = target[3 * g + 2];
  float ox = points[3 * g], oy = points[3 * g + 1], oz = points[3 * g + 2];
  int m = mask[g];
  float cx = ox + tx, cy = oy + ty, cz = oz + tz;  // clean
  float qx = ox + px, qy = oy + py, qz = oz + pz;  // predicted denoised
  float cn = cx * cx + cy * cy + cz * cz;
  float qn = qx * qx + qy * qy + qz * qz;
  float pen = m ? 0.f : 1e9f;
  qnClean[g] = cn;
  qnPred[g] = qn;
  int T = g >> 5, n = g & 31;
  writeA(Apred, T, n, qx, qy, qz, qn + pen);   // dir0 refs = pred-denoised
  writeA(Aclean, T, n, cx, cy, cz, cn + pen);  // dir1 refs = clean
  writeB(Bclean, T, n, cx, cy, cz);            // dir0 queries = clean
  writeB(Bpred, T, n, qx, qy, qz);             // dir1 queries = pred-denoised

  // per-block (single-wave) L1 partial
  float fm = (float)m;
  float l1c = fm * (fabsf(px - tx) + fabsf(py - ty) + fabsf(pz - tz)) * (1.f / 3.f);
  for (int off = 32; off; off >>= 1) l1c += __shfl_down(l1c, off);
  if (tid == 0) l1part[blockIdx.x] = l1c;
}

// Block = (jx in 0..3, qchunk in 0..15, dir*4+b). Each block: 512 queries vs
// 2048 refs, swept in 4 double-buffered 16 KB LDS stages (2-phase pipeline:
// next stage issued before compute, drained by the compiler's vmcnt(0) at the
// barrier). Per-query min accumulates in registers across stages; epilogue is
// one uint atomicMin per query (relu'd values >= 0 -> bit-order == value-order).
__global__ __launch_bounds__(256) void chamfer_kernel(
    const uint4* __restrict__ Apred, const uint4* __restrict__ Aclean,
    const uint4* __restrict__ Bclean, const uint4* __restrict__ Bpred,
    const float* __restrict__ qnClean, const float* __restrict__ qnPred,
    unsigned* __restrict__ minbuf) {
  __shared__ uint4 Asm[2048];  // 32 KB: 2 x 16 ref tiles (double buffer)
  int z = blockIdx.z, dir = z >> 2, b = z & 3;
  const uint4* __restrict__ Ag = dir ? Aclean : Apred;
  const uint4* __restrict__ Bg = dir ? Bpred : Bclean;
  const float* __restrict__ qn = dir ? qnPred : qnClean;
  int jbase = blockIdx.x * 2048;  // refs: 4 stages x 512
  int qbase = blockIdx.y * 512;   // queries
  int tid = threadIdx.x;
  const uint4* Agp = Ag + (size_t)(b * NPTS + jbase) * 2;

  // stage 0 -> buf0 (lane-consecutive 16 B chunks: global_load_lds-compatible)
#pragma unroll
  for (int it = 0; it < 4; it++) lds_load16(Agp + it * 256 + tid, &Asm[it * 256 + tid]);

  // query fragments straight from global (read once per block; coalesced, L2-hot)
  int lane = tid & 63, w = tid >> 6, n = lane & 31;
  const bf16x8* Bb = (const bf16x8*)(Bg + (size_t)(b * NPTS + qbase) * 2);
  bf16x8 bfr[4];
  float acc[4];
#pragma unroll
  for (int q = 0; q < 4; q++) {
    bfr[q] = Bb[(w * 4 + q) * 64 + lane];  // wave owns 4 query tiles (128 queries)
    acc[q] = 1e30f;
  }
  __syncthreads();  // drains vmcnt: stage-0 + B loads complete

  f32x16 zacc = {0.f, 0.f, 0.f, 0.f, 0.f, 0.f, 0.f, 0.f,
                 0.f, 0.f, 0.f, 0.f, 0.f, 0.f, 0.f, 0.f};

  for (int s = 0; s < 4; s++) {
    if (s < 3) {  // issue next stage into the other half; lands at the barrier
      const uint4* An = Agp + (s + 1) * 1024;
      uint4* dst = &Asm[((s + 1) & 1) * 1024];
#pragma unroll
      for (int it = 0; it < 4; it++) lds_load16(An + it * 256 + tid, &dst[it * 256 + tid]);
    }
    const bf16x8* Al = (const bf16x8*)&Asm[(s & 1) * 1024];
#pragma unroll 4
    for (int p = 0; p < 16; p++) {  // stream ref tiles of current stage
      bf16x8 af = Al[p * 64 + lane];
#pragma unroll
      for (int q = 0; q < 4; q++) {
        f32x16 d = __builtin_amdgcn_mfma_f32_32x32x16_bf16(af, bfr[q], zacc, 0, 0, 0);
        // 16 regs = 16 refs (rows) for this lane's query col -> 8 chained v_min3
        acc[q] = fminf(fminf(d[0], d[1]), acc[q]);
        acc[q] = fminf(fminf(d[2], d[3]), acc[q]);
        acc[q] = fminf(fminf(d[4], d[5]), acc[q]);
        acc[q] = fminf(fminf(d[6], d[7]), acc[q]);
        acc[q] = fminf(fminf(d[8], d[9]), acc[q]);
        acc[q] = fminf(fminf(d[10], d[11]), acc[q]);
        acc[q] = fminf(fminf(d[12], d[13]), acc[q]);
        acc[q] = fminf(fminf(d[14], d[15]), acc[q]);
      }
    }
    __syncthreads();  // compiler emits vmcnt(0) lgkmcnt(0): next stage ready,
                      // this buffer safe to overwrite two stages later
  }

  // epilogue: combine row halves, add query norm, relu, atomic min (4-way
  // contention per address across the jx blocks)
  unsigned* __restrict__ Mq = minbuf + (size_t)z * NPTS + qbase;
#pragma unroll
  for (int q = 0; q < 4; q++) {
    float v = fminf(acc[q], __shfl_xor(acc[q], 32));
    int qi = (w * 4 + q) * 32 + n;
    if (lane < 32) {
      float r = fmaxf(v + qn[b * NPTS + qbase + qi], 0.f);
      atomicMin(&Mq[qi], __float_as_uint(r));
    }
  }
}

// 64 blocks: 8 per (dir,b) slice, 1024 queries each. Mask + sum the final
// per-query mins, one atomicAdd per block; the LAST block to finish (device-
// scope ticket) computes the output scalar -- no separate final kernel.
__global__ __launch_bounds__(256) void reduce_kernel(
    const int* __restrict__ mask, const unsigned* __restrict__ minbuf,
    const float* __restrict__ l1part, Accum* __restrict__ acc,
    float* __restrict__ out) {
  int blk = blockIdx.x;
  int slice = blk >> 3, sub = blk & 7;
  int dir = slice >> 2, bb = slice & 3;
  int t = threadIdx.x;
  const unsigned* __restrict__ P = minbuf + (size_t)slice * NPTS + sub * 1024;
  const int* __restrict__ M = mask + bb * NPTS + sub * 1024;
  float s = 0.f, c = 0.f;
  for (int i = t; i < 1024; i += 256) {
    float m = (float)M[i];
    s += m * __uint_as_float(P[i]);
    c += m;
  }
  for (int off = 32; off; off >>= 1) {
    s += __shfl_down(s, off);
    c += __shfl_down(c, off);
  }
  __shared__ float rs[4], rc[4];
  __shared__ int lastf;
  int wv = t >> 6;
  if ((t & 63) == 0) { rs[wv] = s; rc[wv] = c; }
  __syncthreads();
  if (t == 0) {
    atomicAdd(&acc->minsum[slice], rs[0] + rs[1] + rs[2] + rs[3]);
    if (dir == 0) atomicAdd(&acc->count[bb], rc[0] + rc[1] + rc[2] + rc[3]);
    __threadfence();  // release: make our adds visible before ticket
    unsigned tk = atomicAdd(&acc->ticket, 1u);
    lastf = (tk == 63u);
    if (tk == 63u) __threadfence();  // acquire: see everyone's adds
  }
  __syncthreads();
  if (!lastf) return;

  // final: this block sums the 512 L1 partials + combines accumulators
  float l1 = l1part[t] + l1part[t + 256];
  for (int off = 32; off; off >>= 1) l1 += __shfl_down(l1, off);
  __shared__ float rl[4];
  if ((t & 63) == 0) rl[t >> 6] = l1;
  __syncthreads();
  if (t == 0) {
    float l1s = rl[0] + rl[1] + rl[2] + rl[3];
    volatile float* va = (volatile float*)acc;  // count[0..3], minsum[4..11]
    float msum = 0.f, cham = 0.f;
#pragma unroll
    for (int b = 0; b < BATCH; b++) {
      float cb = va[b];
      msum += cb;
      cham += (va[4 + b] + va[8 + b]) / fmaxf(cb, 1.f);
    }
    out[0] = 0.5f * (l1s / msum + cham * (1.f / BATCH));
  }
}

extern "C" void kernel_launch(void* const* d_in, const int* in_sizes, int n_in,
                              void* d_out, int out_size, void* d_ws, size_t ws_size,
                              hipStream_t stream) {
  const float* pred   = (const float*)d_in[0];
  const float* target = (const float*)d_in[1];
  const int*   mask   = (const int*)d_in[2];
  const float* points = (const float*)d_in[3];
  float* out = (float*)d_out;

  const int NP = BATCH * NPTS;  // 32768
  uint4* Apred  = (uint4*)d_ws;            // 1 MB each
  uint4* Aclean = Apred + NP * 2;
  uint4* Bclean = Aclean + NP * 2;
  uint4* Bpred  = Bclean + NP * 2;
  float* qnClean = (float*)(Bpred + NP * 2);   // 128 KB each
  float* qnPred  = qnClean + NP;
  unsigned* minbuf = (unsigned*)(qnPred + NP); // 8*NPTS u32 = 256 KB
  float* l1part  = (float*)(minbuf + 2 * NP);  // 512 floats
  Accum* acc     = (Accum*)(l1part + 512);

  prep_kernel<<<NP / 64, 64, 0, stream>>>(
      pred, target, mask, points, Apred, Aclean, Bclean, Bpred,
      qnClean, qnPred, minbuf, l1part, acc);

  dim3 grid(4, NPTS / 512, 2 * BATCH);  // (4,16,8) = 512 blocks
  chamfer_kernel<<<grid, 256, 0, stream>>>(
      Apred, Aclean, Bclean, Bpred, qnClean, qnPred, minbuf);

  reduce_kernel<<<64, 256, 0, stream>>>(mask, minbuf, l1part, acc, out);
}

// Round 2
// 95.022 us; speedup vs baseline: 1.0208x; 1.0208x over previous
//
#include <hip/hip_runtime.h>
#include <stdint.h>

#define NPTS 8192
#define BATCH 4

typedef __attribute__((ext_vector_type(8))) short bf16x8;   // 8 bf16 = 4 VGPRs
typedef __attribute__((ext_vector_type(16))) float f32x16;  // 32x32 MFMA acc

struct Accum {
  float count[4];    // [b] valid-point counts
  float minsum[8];   // [dir*4+b] masked min sums
  unsigned ticket;   // last-block-done counter (reset by prep each launch)
  unsigned pad[3];
};

__device__ __forceinline__ unsigned short f2bf(float x) {  // RNE fp32->bf16
  union { float f; unsigned u; } v; v.f = x;
  unsigned r = v.u + 0x7FFFu + ((v.u >> 16) & 1u);
  return (unsigned short)(r >> 16);
}
__device__ __forceinline__ float bf2f(unsigned short h) {
  union { float f; unsigned u; } v; v.u = ((unsigned)h) << 16;
  return v.f;
}

using as1_t = __attribute__((address_space(1))) const unsigned int;
using as3_t = __attribute__((address_space(3))) unsigned int;
__device__ __forceinline__ void lds_load16(const void* g, void* l) {
  __builtin_amdgcn_global_load_lds((as1_t*)g, (as3_t*)l, 16, 0, 0);
}

// Pack layout (fragment order): per 32-point tile T, 64 chunks of 16 B:
// chunk T*64 + h*32 + n = K-slots [8h..8h+7] of point T*32+n  (== chunk T*64+lane
// for MFMA lane = h*32+n, so frag load is lane-consecutive 16 B -> conflict-free).
// A (ref):   k0-3=[-2x_h,-2x_h,-2x_l,-2x_l] k4-7=y k8-11=z k12-14=3-split(norm+pen) k15=0
// B (query): k0-3=[x_h,x_l,x_h,x_l]         k4-7=y k8-11=z k12-14=[1,1,1]          k15=0
// => D[ref m][query n] = (norm_r + pen) - 2 q.r  (query norm added in epilogue;
// exact hi/lo bf16 product pairing, norm exact to ~4e-7)
__device__ __forceinline__ void writeA(uint4* P, int T, int n,
                                       float x, float y, float z, float nn) {
  float ax = -2.f * x, ay = -2.f * y, az = -2.f * z;
  unsigned xh = f2bf(ax), xl = f2bf(ax - bf2f(xh));
  unsigned yh = f2bf(ay), yl = f2bf(ay - bf2f(yh));
  unsigned zh = f2bf(az), zl = f2bf(az - bf2f(zh));
  unsigned nh = f2bf(nn);
  float rem = nn - bf2f((unsigned short)nh);
  unsigned nm = f2bf(rem);
  unsigned nl = f2bf(rem - bf2f((unsigned short)nm));
  uint4 h0, h1;
  h0.x = xh | (xh << 16); h0.y = xl | (xl << 16);
  h0.z = yh | (yh << 16); h0.w = yl | (yl << 16);
  h1.x = zh | (zh << 16); h1.y = zl | (zl << 16);
  h1.z = nh | (nm << 16); h1.w = nl;
  P[T * 64 + n] = h0;
  P[T * 64 + 32 + n] = h1;
}
__device__ __forceinline__ void writeB(uint4* P, int T, int n,
                                       float x, float y, float z) {
  unsigned xh = f2bf(x), xl = f2bf(x - bf2f((unsigned short)xh));
  unsigned yh = f2bf(y), yl = f2bf(y - bf2f((unsigned short)yh));
  unsigned zh = f2bf(z), zl = f2bf(z - bf2f((unsigned short)zh));
  const unsigned ONE = 0x3F80u;
  unsigned ux = xh | (xl << 16), uy = yh | (yl << 16), uz = zh | (zl << 16);
  uint4 h0, h1;
  h0.x = ux; h0.y = ux; h0.z = uy; h0.w = uy;
  h1.x = uz; h1.y = uz; h1.z = ONE | (ONE << 16); h1.w = ONE;
  P[T * 64 + n] = h0;
  P[T * 64 + 32 + n] = h1;
}

// 512 blocks x 64 threads: 2 waves/CU for the latency-bound pack.
__global__ __launch_bounds__(64) void prep_kernel(
    const float* __restrict__ pred, const float* __restrict__ target,
    const int* __restrict__ mask, const float* __restrict__ points,
    uint4* __restrict__ Apred, uint4* __restrict__ Aclean,
    uint4* __restrict__ Bclean, uint4* __restrict__ Bpred,
    float* __restrict__ qnClean, float* __restrict__ qnPred,
    unsigned* __restrict__ minbuf, float* __restrict__ l1part,
    Accum* __restrict__ acc) {
  int tid = threadIdx.x;
  int g = blockIdx.x * 64 + tid;  // 512*64 = BATCH*NPTS
  if (g < 16) ((unsigned*)acc)[g] = 0u;  // zero counts/minsums/ticket
  // init per-query running-min buffer to +inf (8 slices x 8192 = 2*32768)
  minbuf[g] = 0x7F800000u;
  minbuf[g + BATCH * NPTS] = 0x7F800000u;

  float px = pred[3 * g], py = pred[3 * g + 1], pz = pred[3 * g + 2];
  float tx = target[3 * g], ty = target[3 * g + 1], tz = target[3 * g + 2];
  float ox = points[3 * g], oy = points[3 * g + 1], oz = points[3 * g + 2];
  int m = mask[g];
  float cx = ox + tx, cy = oy + ty, cz = oz + tz;  // clean
  float qx = ox + px, qy = oy + py, qz = oz + pz;  // predicted denoised
  float cn = cx * cx + cy * cy + cz * cz;
  float qn = qx * qx + qy * qy + qz * qz;
  float pen = m ? 0.f : 1e9f;
  qnClean[g] = cn;
  qnPred[g] = qn;
  int T = g >> 5, n = g & 31;
  writeA(Apred, T, n, qx, qy, qz, qn + pen);   // dir0 refs = pred-denoised
  writeA(Aclean, T, n, cx, cy, cz, cn + pen);  // dir1 refs = clean
  writeB(Bclean, T, n, cx, cy, cz);            // dir0 queries = clean
  writeB(Bpred, T, n, qx, qy, qz);             // dir1 queries = pred-denoised

  // per-block (single-wave) L1 partial
  float fm = (float)m;
  float l1c = fm * (fabsf(px - tx) + fabsf(py - ty) + fabsf(pz - tz)) * (1.f / 3.f);
  for (int off = 32; off; off >>= 1) l1c += __shfl_down(l1c, off);
  if (tid == 0) l1part[blockIdx.x] = l1c;
}

// Block = (jchunk 0..15, qchunk 0..15, dir*4+b): 512 refs x 512 queries,
// 16 KB single-stage LDS, ONE barrier, 64 back-to-back MFMA+min3 per block.
// 2048 blocks (~8/CU resident) give inter-block TLP that hides the staging
// burst and the epilogue atomics (round-0 geometry: this measured faster than
// the 512-block 4-stage pipeline, whose per-stage vmcnt(0) barrier drains
// could not be hidden at 2 blocks/CU). Epilogue: one fire-and-forget uint
// atomicMin per query (relu'd values >= 0 -> bit-order == value-order).
__global__ __launch_bounds__(256) void chamfer_kernel(
    const uint4* __restrict__ Apred, const uint4* __restrict__ Aclean,
    const uint4* __restrict__ Bclean, const uint4* __restrict__ Bpred,
    const float* __restrict__ qnClean, const float* __restrict__ qnPred,
    unsigned* __restrict__ minbuf) {
  __shared__ uint4 Asm[1024];  // 16 KB: 16 ref tiles
  int z = blockIdx.z, dir = z >> 2, b = z & 3;
  const uint4* __restrict__ Ag = dir ? Aclean : Apred;
  const uint4* __restrict__ Bg = dir ? Bpred : Bclean;
  const float* __restrict__ qn = dir ? qnPred : qnClean;
  int jbase = blockIdx.x * 512;  // refs
  int qbase = blockIdx.y * 512;  // queries
  int tid = threadIdx.x;

  // stage refs -> LDS (lane-consecutive 16 B chunks: global_load_lds-compatible)
  const uint4* Agp = Ag + (size_t)(b * NPTS + jbase) * 2;
#pragma unroll
  for (int it = 0; it < 4; it++) lds_load16(Agp + it * 256 + tid, &Asm[it * 256 + tid]);

  // query fragments straight from global (read once per wave; coalesced, L2-hot)
  int lane = tid & 63, w = tid >> 6, n = lane & 31;
  const bf16x8* Bb = (const bf16x8*)(Bg + (size_t)(b * NPTS + qbase) * 2);
  bf16x8 bfr[4];
  float acc[4];
#pragma unroll
  for (int q = 0; q < 4; q++) {
    bfr[q] = Bb[(w * 4 + q) * 64 + lane];  // wave owns 4 query tiles (128 queries)
    acc[q] = 1e30f;
  }
  __syncthreads();  // drains vmcnt: LDS staging + B loads both complete

  const bf16x8* Al = (const bf16x8*)Asm;
  f32x16 zacc = {0.f, 0.f, 0.f, 0.f, 0.f, 0.f, 0.f, 0.f,
                 0.f, 0.f, 0.f, 0.f, 0.f, 0.f, 0.f, 0.f};

#pragma unroll 4
  for (int p = 0; p < 16; p++) {  // stream ref tiles
    bf16x8 af = Al[p * 64 + lane];
#pragma unroll
    for (int q = 0; q < 4; q++) {
      f32x16 d = __builtin_amdgcn_mfma_f32_32x32x16_bf16(af, bfr[q], zacc, 0, 0, 0);
      // 16 regs = 16 refs (rows) for this lane's query col -> 8 chained v_min3
      acc[q] = fminf(fminf(d[0], d[1]), acc[q]);
      acc[q] = fminf(fminf(d[2], d[3]), acc[q]);
      acc[q] = fminf(fminf(d[4], d[5]), acc[q]);
      acc[q] = fminf(fminf(d[6], d[7]), acc[q]);
      acc[q] = fminf(fminf(d[8], d[9]), acc[q]);
      acc[q] = fminf(fminf(d[10], d[11]), acc[q]);
      acc[q] = fminf(fminf(d[12], d[13]), acc[q]);
      acc[q] = fminf(fminf(d[14], d[15]), acc[q]);
    }
  }

  // epilogue: combine row halves, add query norm, relu, fire-and-forget
  // atomicMin (16-way per-address contention across jchunk blocks, no return)
  unsigned* __restrict__ Mq = minbuf + (size_t)z * NPTS + qbase;
#pragma unroll
  for (int q = 0; q < 4; q++) {
    float v = fminf(acc[q], __shfl_xor(acc[q], 32));
    int qi = (w * 4 + q) * 32 + n;
    if (lane < 32) {
      float r = fmaxf(v + qn[b * NPTS + qbase + qi], 0.f);
      atomicMin(&Mq[qi], __float_as_uint(r));
    }
  }
}

// 64 blocks: 8 per (dir,b) slice, 1024 queries each. Mask + sum the final
// per-query mins, one atomicAdd per block; the LAST block to finish (device-
// scope ticket) computes the output scalar -- no separate final kernel.
__global__ __launch_bounds__(256) void reduce_kernel(
    const int* __restrict__ mask, const unsigned* __restrict__ minbuf,
    const float* __restrict__ l1part, Accum* __restrict__ acc,
    float* __restrict__ out) {
  int blk = blockIdx.x;
  int slice = blk >> 3, sub = blk & 7;
  int dir = slice >> 2, bb = slice & 3;
  int t = threadIdx.x;
  const unsigned* __restrict__ P = minbuf + (size_t)slice * NPTS + sub * 1024;
  const int* __restrict__ M = mask + bb * NPTS + sub * 1024;
  float s = 0.f, c = 0.f;
  for (int i = t; i < 1024; i += 256) {
    float m = (float)M[i];
    s += m * __uint_as_float(P[i]);
    c += m;
  }
  for (int off = 32; off; off >>= 1) {
    s += __shfl_down(s, off);
    c += __shfl_down(c, off);
  }
  __shared__ float rs[4], rc[4];
  __shared__ int lastf;
  int wv = t >> 6;
  if ((t & 63) == 0) { rs[wv] = s; rc[wv] = c; }
  __syncthreads();
  if (t == 0) {
    atomicAdd(&acc->minsum[slice], rs[0] + rs[1] + rs[2] + rs[3]);
    if (dir == 0) atomicAdd(&acc->count[bb], rc[0] + rc[1] + rc[2] + rc[3]);
    __threadfence();  // release: make our adds visible before ticket
    unsigned tk = atomicAdd(&acc->ticket, 1u);
    lastf = (tk == 63u);
    if (tk == 63u) __threadfence();  // acquire: see everyone's adds
  }
  __syncthreads();
  if (!lastf) return;

  // final: this block sums the 512 L1 partials + combines accumulators
  float l1 = l1part[t] + l1part[t + 256];
  for (int off = 32; off; off >>= 1) l1 += __shfl_down(l1, off);
  __shared__ float rl[4];
  if ((t & 63) == 0) rl[t >> 6] = l1;
  __syncthreads();
  if (t == 0) {
    float l1s = rl[0] + rl[1] + rl[2] + rl[3];
    volatile float* va = (volatile float*)acc;  // count[0..3], minsum[4..11]
    float msum = 0.f, cham = 0.f;
#pragma unroll
    for (int b = 0; b < BATCH; b++) {
      float cb = va[b];
      msum += cb;
      cham += (va[4 + b] + va[8 + b]) / fmaxf(cb, 1.f);
    }
    out[0] = 0.5f * (l1s / msum + cham * (1.f / BATCH));
  }
}

extern "C" void kernel_launch(void* const* d_in, const int* in_sizes, int n_in,
                              void* d_out, int out_size, void* d_ws, size_t ws_size,
                              hipStream_t stream) {
  const float* pred   = (const float*)d_in[0];
  const float* target = (const float*)d_in[1];
  const int*   mask   = (const int*)d_in[2];
  const float* points = (const float*)d_in[3];
  float* out = (float*)d_out;

  const int NP = BATCH * NPTS;  // 32768
  uint4* Apred  = (uint4*)d_ws;            // 1 MB each
  uint4* Aclean = Apred + NP * 2;
  uint4* Bclean = Aclean + NP * 2;
  uint4* Bpred  = Bclean + NP * 2;
  float* qnClean = (float*)(Bpred + NP * 2);   // 128 KB each
  float* qnPred  = qnClean + NP;
  unsigned* minbuf = (unsigned*)(qnPred + NP); // 8*NPTS u32 = 256 KB
  float* l1part  = (float*)(minbuf + 2 * NP);  // 512 floats
  Accum* acc     = (Accum*)(l1part + 512);

  prep_kernel<<<NP / 64, 64, 0, stream>>>(
      pred, target, mask, points, Apred, Aclean, Bclean, Bpred,
      qnClean, qnPred, minbuf, l1part, acc);

  dim3 grid(NPTS / 512, NPTS / 512, 2 * BATCH);  // (16,16,8) = 2048 blocks
  chamfer_kernel<<<grid, 256, 0, stream>>>(
      Apred, Aclean, Bclean, Bpred, qnClean, qnPred, minbuf);

  reduce_kernel<<<64, 256, 0, stream>>>(mask, minbuf, l1part, acc, out);
}